// Round 3
// baseline (4932.885 us; speedup 1.0000x reference)
//
#include <hip/hip_runtime.h>
#include <math.h>

// Problem constants (B, ST, TT, H, E, V, O) = (64, 1024, 256, 512, 512, 32, 31)
#define B_   64
#define ST_  1024
#define TT_  256
#define H_   512
#define E_   512
#define V_   32
#define O_   31
#define G3_  1536   // 3*H
#define NGRP_ 8     // batch groups (bc), 64 WGs each share one barrier
#define CSTRIDE_ 64 // barrier counter stride in u32 (256 B -> own cache line)

// ---------------------------------------------------------------------------
// coherent-point access helpers: sc0 sc1 = write-through / L2-bypass on gfx950
// ---------------------------------------------------------------------------
__device__ __forceinline__ void load4_sc(const float* p0, const float* p1,
                                         const float* p2, const float* p3,
                                         float4& r0, float4& r1,
                                         float4& r2, float4& r3) {
    asm volatile(
        "global_load_dwordx4 %0, %4, off sc0 sc1\n\t"
        "global_load_dwordx4 %1, %5, off sc0 sc1\n\t"
        "global_load_dwordx4 %2, %6, off sc0 sc1\n\t"
        "global_load_dwordx4 %3, %7, off sc0 sc1\n\t"
        "s_waitcnt vmcnt(0)"
        : "=&v"(r0), "=&v"(r1), "=&v"(r2), "=&v"(r3)
        : "v"(p0), "v"(p1), "v"(p2), "v"(p3)
        : "memory");
}

__device__ __forceinline__ void store_sc(float* p, float v) {
    asm volatile("global_store_dword %0, %1, off sc0 sc1"
                 :: "v"(p), "v"(v) : "memory");
}

// ---------------------------------------------------------------------------
// K0a: giV[v, n] = sum_k embed[v,k] * W_ih[n,k] + b_ih[n]   (32 x 1536)
// ---------------------------------------------------------------------------
__global__ __launch_bounds__(256) void k_giv(const float* __restrict__ embed,
                                             const float* __restrict__ W_ih,
                                             const float* __restrict__ b_ih,
                                             float* __restrict__ giV) {
    int idx = blockIdx.x * 256 + threadIdx.x;       // 0 .. 49151
    if (idx >= V_ * G3_) return;
    int v = idx / G3_, n = idx % G3_;
    const float4* e4 = (const float4*)(embed + v * E_);
    const float4* w4 = (const float4*)(W_ih + (size_t)n * E_);
    float acc = 0.f;
#pragma unroll 4
    for (int k = 0; k < E_ / 4; ++k) {
        float4 a = e4[k], b = w4[k];
        acc += a.x * b.x + a.y * b.y + a.z * b.z + a.w * b.w;
    }
    giV[idx] = acc + b_ih[n];
}

// ---------------------------------------------------------------------------
// K0b: transpose fc_W -> fc_Wt (1024 x 32) and zero the barrier counters
// (one counter per (t, bc), each on its own 256 B line)
// ---------------------------------------------------------------------------
__global__ __launch_bounds__(256) void k_fcw_t(const float* __restrict__ fc_W,
                                               float* __restrict__ fc_Wt,
                                               unsigned* __restrict__ cnt) {
    int idx = blockIdx.x * 256 + threadIdx.x;       // 0 .. 32767
    int k = idx >> 5, o = idx & 31;
    fc_Wt[idx] = (o < O_) ? fc_W[(size_t)o * 1024 + k] : 0.f;
    if (idx < TT_ * NGRP_) cnt[(size_t)idx * CSTRIDE_] = 0u;
}

// ---------------------------------------------------------------------------
// K1p: persistent GRU, all 256 steps in one dispatch.
// Grid = 512 WGs (bc=8 x jc=64) x 256 thr, 2 WGs/CU (cooperative launch used
// ONLY for the co-residency guarantee — no grid.sync()).
// W_hh read straight from global (L2-resident, 8-lane broadcast merge) —
// LDS holds only the h tile, keeping the LDS port off the critical path.
// Cross-WG h exchange via sc0/sc1 stores+loads through the coherent point;
// per-step sync = 8 independent 64-WG counter barriers, one 256B line each.
// Math identical to the verified per-step kernel.
// ---------------------------------------------------------------------------
__global__ __launch_bounds__(256, 2) void k_gru_persist(
        const float* __restrict__ h0,
        const float* __restrict__ giV,
        const int* __restrict__ trg,
        const float* __restrict__ W_hh,
        const float* __restrict__ b_hh,
        float* __restrict__ h_all,
        unsigned* __restrict__ cnt) {
    __shared__ float hsf[4224];   // 8 rows x 4 ks x 132 floats (padded)

    int tid = threadIdx.x;
    int jc = blockIdx.x & 63, bc = blockIdx.x >> 6;
    int b0 = bc * 8, j0 = jc * 8;

    int bl = tid & 7;                            // batch within block
    int ks = (tid >> 3) & 3;                     // K-split id (128 each)
    int jl = tid >> 5;                           // j within block
    int j  = j0 + jl;
    int k0 = ks * 128;

    // loop-invariant W pointers (global; L2-resident after first step)
    const float4* w0 = (const float4*)(W_hh + (size_t)(j         ) * H_ + k0);
    const float4* w1 = (const float4*)(W_hh + (size_t)(j +   H_  ) * H_ + k0);
    const float4* w2 = (const float4*)(W_hh + (size_t)(j + 2 * H_) * H_ + k0);
    const float4* h4 = (const float4*)&hsf[bl * 528 + ks * 132];

    float bhr = b_hh[j], bhz = b_hh[H_ + j], bhn = b_hh[2 * H_ + j];

    // staging geometry: k4s = float4 index within a row (constant per thread),
    // rows handled: (tid>>7) + 2*i for i=0..3
    int k4s = tid & 127, rw = tid >> 7;
    int lds_off = (k4s >> 5) * 132 + (k4s & 31) * 4;

    for (int t = 0; t < TT_; ++t) {
        if (t == 0) {
#pragma unroll
            for (int i = 0; i < 4; ++i) {
                int row = rw + 2 * i;
                float4 v = *(const float4*)(h0 + (size_t)(b0 + row) * H_ + k4s * 4);
                *(float4*)&hsf[row * 528 + lds_off] = v;
            }
        } else {
            const float* pb = h_all + (size_t)(t - 1) * H_ + (size_t)k4s * 4;
            const float* p0v = pb + (size_t)(b0 + rw + 0) * (TT_ * H_);
            const float* p1v = pb + (size_t)(b0 + rw + 2) * (TT_ * H_);
            const float* p2v = pb + (size_t)(b0 + rw + 4) * (TT_ * H_);
            const float* p3v = pb + (size_t)(b0 + rw + 6) * (TT_ * H_);
            float4 r0v, r1v, r2v, r3v;
            load4_sc(p0v, p1v, p2v, p3v, r0v, r1v, r2v, r3v);
            *(float4*)&hsf[(rw + 0) * 528 + lds_off] = r0v;
            *(float4*)&hsf[(rw + 2) * 528 + lds_off] = r1v;
            *(float4*)&hsf[(rw + 4) * 528 + lds_off] = r2v;
            *(float4*)&hsf[(rw + 6) * 528 + lds_off] = r3v;
        }
        __syncthreads();

        float sr = 0.f, sz = 0.f, sn = 0.f;
#pragma unroll 8
        for (int k = 0; k < 32; ++k) {
            float4 hv = h4[k];
            float4 a = w0[k], c = w1[k], d = w2[k];
            sr += hv.x * a.x + hv.y * a.y + hv.z * a.z + hv.w * a.w;
            sz += hv.x * c.x + hv.y * c.y + hv.z * c.z + hv.w * c.w;
            sn += hv.x * d.x + hv.y * d.y + hv.z * d.z + hv.w * d.w;
        }
        sr += __shfl_xor(sr, 8);  sr += __shfl_xor(sr, 16);
        sz += __shfl_xor(sz, 8);  sz += __shfl_xor(sz, 16);
        sn += __shfl_xor(sn, 8);  sn += __shfl_xor(sn, 16);

        if (ks == 0) {
            int b = b0 + bl;
            int tok = trg[(size_t)b * TT_ + t];
            const float* gv = giV + (size_t)tok * G3_;
            float r = 1.f / (1.f + expf(-(gv[j] + sr + bhr)));
            float z = 1.f / (1.f + expf(-(gv[H_ + j] + sz + bhz)));
            float n = tanhf(gv[2 * H_ + j] + r * (sn + bhn));
            float hpv = hsf[bl * 528 + (j >> 7) * 132 + (j & 127)];
            store_sc(h_all + (size_t)b * TT_ * H_ + (size_t)t * H_ + j,
                     (1.f - z) * n + z * hpv);
        }

        // make this wave's write-through stores reach the coherent point
        asm volatile("s_waitcnt vmcnt(0)" ::: "memory");
        __syncthreads();   // all waves of the WG done writing h[t]

        if (t < TT_ - 1) {
            if (tid == 0) {
                unsigned* c = cnt + (size_t)(t * NGRP_ + bc) * CSTRIDE_;
                __hip_atomic_fetch_add(c, 1u, __ATOMIC_RELAXED,
                                       __HIP_MEMORY_SCOPE_AGENT);
                int guard = 0;
                while (__hip_atomic_load(c, __ATOMIC_RELAXED,
                                         __HIP_MEMORY_SCOPE_AGENT) < 64u) {
                    __builtin_amdgcn_s_sleep(1);
                    if (++guard > (1 << 24)) break;   // safety valve
                }
            }
            __syncthreads();   // release whole WG once group barrier passed
        }
    }
}

// ---------------------------------------------------------------------------
// K1 (fallback): one GRU step per launch — used only if cooperative launch
// is unavailable. Identical math.
// ---------------------------------------------------------------------------
__global__ __launch_bounds__(256) void k_gru_step(const float* __restrict__ h_prev,
                                                  int hp_stride,
                                                  const float* __restrict__ giV,
                                                  const int* __restrict__ trg,
                                                  const float* __restrict__ W_hh,
                                                  const float* __restrict__ b_hh,
                                                  float* __restrict__ h_all,
                                                  int t) {
    __shared__ float hs[8][520];
    int tid = threadIdx.x;
    int jc = blockIdx.x & 63, bc = blockIdx.x >> 6;
    int b0 = bc * 8;

#pragma unroll
    for (int i = 0; i < 4; ++i) {
        int fi = tid + i * 256;
        int bl2 = fi >> 7, k4 = fi & 127;
        float4 v = *(const float4*)(h_prev + (size_t)(b0 + bl2) * hp_stride + k4 * 4);
        *(float4*)&hs[bl2][k4 * 4] = v;
    }
    __syncthreads();

    int bl = tid & 7;
    int ks = (tid >> 3) & 3;
    int jl = tid >> 5;
    int j  = jc * 8 + jl;
    int k0 = ks * 128;

    const float4* w0 = (const float4*)(W_hh + (size_t)(j         ) * H_ + k0);
    const float4* w1 = (const float4*)(W_hh + (size_t)(j +   H_  ) * H_ + k0);
    const float4* w2 = (const float4*)(W_hh + (size_t)(j + 2 * H_) * H_ + k0);
    const float4* h4 = (const float4*)&hs[bl][k0];

    float sr = 0.f, sz = 0.f, sn = 0.f;
#pragma unroll 8
    for (int k = 0; k < 32; ++k) {
        float4 hv = h4[k];
        float4 a = w0[k], c = w1[k], d = w2[k];
        sr += hv.x * a.x + hv.y * a.y + hv.z * a.z + hv.w * a.w;
        sz += hv.x * c.x + hv.y * c.y + hv.z * c.z + hv.w * c.w;
        sn += hv.x * d.x + hv.y * d.y + hv.z * d.z + hv.w * d.w;
    }
    sr += __shfl_xor(sr, 8);  sr += __shfl_xor(sr, 16);
    sz += __shfl_xor(sz, 8);  sz += __shfl_xor(sz, 16);
    sn += __shfl_xor(sn, 8);  sn += __shfl_xor(sn, 16);

    if (ks == 0) {
        int b = b0 + bl;
        int tok = trg[(size_t)b * TT_ + t];
        const float* gv = giV + (size_t)tok * G3_;
        float gh_r = sr + b_hh[j];
        float gh_z = sz + b_hh[H_ + j];
        float gh_n = sn + b_hh[2 * H_ + j];
        float r = 1.f / (1.f + expf(-(gv[j] + gh_r)));
        float z = 1.f / (1.f + expf(-(gv[H_ + j] + gh_z)));
        float n = tanhf(gv[2 * H_ + j] + r * gh_n);
        float hp = hs[bl][j];
        h_all[(size_t)b * TT_ * H_ + (size_t)t * H_ + j] = (1.f - z) * n + z * hp;
    }
}

// FMA micro-kernel helper for the 4x4 register tiles
#define FMA16(a, bb)                                                     \
    acc[0][0] = fmaf(a.x, bb.x, acc[0][0]);                              \
    acc[0][1] = fmaf(a.x, bb.y, acc[0][1]);                              \
    acc[0][2] = fmaf(a.x, bb.z, acc[0][2]);                              \
    acc[0][3] = fmaf(a.x, bb.w, acc[0][3]);                              \
    acc[1][0] = fmaf(a.y, bb.x, acc[1][0]);                              \
    acc[1][1] = fmaf(a.y, bb.y, acc[1][1]);                              \
    acc[1][2] = fmaf(a.y, bb.z, acc[1][2]);                              \
    acc[1][3] = fmaf(a.y, bb.w, acc[1][3]);                              \
    acc[2][0] = fmaf(a.z, bb.x, acc[2][0]);                              \
    acc[2][1] = fmaf(a.z, bb.y, acc[2][1]);                              \
    acc[2][2] = fmaf(a.z, bb.z, acc[2][2]);                              \
    acc[2][3] = fmaf(a.z, bb.w, acc[2][3]);                              \
    acc[3][0] = fmaf(a.w, bb.x, acc[3][0]);                              \
    acc[3][1] = fmaf(a.w, bb.y, acc[3][1]);                              \
    acc[3][2] = fmaf(a.w, bb.z, acc[3][2]);                              \
    acc[3][3] = fmaf(a.w, bb.w, acc[3][3]);

// ---------------------------------------------------------------------------
// K2: scores[b, t, s] = sum_k h_all[b,t,k] * enc[b,s,k]   (NT GEMM per batch)
// ---------------------------------------------------------------------------
__global__ __launch_bounds__(256) void k_scores(const float* __restrict__ h_all,
                                                const float* __restrict__ enc,
                                                float* __restrict__ wgt) {
    __shared__ float As[16][68];
    __shared__ float Bs[16][68];
    int b  = blockIdx.z;
    int m0 = blockIdx.y * 64, n0 = blockIdx.x * 64;
    int tid = threadIdx.x;
    int tx = tid & 15, ty = tid >> 4;
    int lr = tid >> 2, lk = (tid & 3) * 4;

    const float* Abase = h_all + (size_t)b * TT_ * H_ + (size_t)(m0 + lr) * H_ + lk;
    const float* Bbase = enc   + (size_t)b * ST_ * H_ + (size_t)(n0 + lr) * H_ + lk;

    float acc[4][4] = {};
    for (int k0 = 0; k0 < H_; k0 += 16) {
        float4 av = *(const float4*)(Abase + k0);
        float4 bv = *(const float4*)(Bbase + k0);
        __syncthreads();
        As[lk + 0][lr] = av.x; As[lk + 1][lr] = av.y;
        As[lk + 2][lr] = av.z; As[lk + 3][lr] = av.w;
        Bs[lk + 0][lr] = bv.x; Bs[lk + 1][lr] = bv.y;
        Bs[lk + 2][lr] = bv.z; Bs[lk + 3][lr] = bv.w;
        __syncthreads();
#pragma unroll
        for (int kk = 0; kk < 16; ++kk) {
            float4 a  = *(const float4*)&As[kk][ty * 4];
            float4 bb = *(const float4*)&Bs[kk][tx * 4];
            FMA16(a, bb)
        }
    }
#pragma unroll
    for (int i = 0; i < 4; ++i)
#pragma unroll
        for (int jj = 0; jj < 4; ++jj)
            wgt[(size_t)b * TT_ * ST_ + (size_t)(m0 + ty * 4 + i) * ST_ + (n0 + tx * 4 + jj)] = acc[i][jj];
}

// ---------------------------------------------------------------------------
// K3: masked softmax over s (row length 1024). One block per (b, t) row.
// ---------------------------------------------------------------------------
__global__ __launch_bounds__(256) void k_softmax(float* __restrict__ wgt,
                                                 const int* __restrict__ source_len) {
    __shared__ float red[8];
    int row = blockIdx.x;            // b*TT + t
    int b = row >> 8;
    int slen = source_len[b];
    float* W = wgt + (size_t)row * ST_;
    int tid = threadIdx.x;

    float v[4];
    float mx = -3.0e38f;
#pragma unroll
    for (int i = 0; i < 4; ++i) {
        int s = tid + i * 256;
        v[i] = (s < slen) ? W[s] : -1e9f;
        mx = fmaxf(mx, v[i]);
    }
#pragma unroll
    for (int off = 32; off; off >>= 1) mx = fmaxf(mx, __shfl_xor(mx, off));
    int wv = tid >> 6;
    if ((tid & 63) == 0) red[wv] = mx;
    __syncthreads();
    mx = fmaxf(fmaxf(red[0], red[1]), fmaxf(red[2], red[3]));

    float sm = 0.f;
#pragma unroll
    for (int i = 0; i < 4; ++i) {
        v[i] = expf(v[i] - mx);
        sm += v[i];
    }
#pragma unroll
    for (int off = 32; off; off >>= 1) sm += __shfl_xor(sm, off);
    if ((tid & 63) == 0) red[4 + wv] = sm;
    __syncthreads();
    sm = red[4] + red[5] + red[6] + red[7];
    float inv = 1.f / sm;
#pragma unroll
    for (int i = 0; i < 4; ++i)
        W[tid + i * 256] = v[i] * inv;
}

// ---------------------------------------------------------------------------
// K4: ctx[b, t, n] = sum_s wgt[b,t,s] * enc[b,s,n]   (NN GEMM per batch)
// ---------------------------------------------------------------------------
__global__ __launch_bounds__(256) void k_ctx(const float* __restrict__ wgt,
                                             const float* __restrict__ enc,
                                             float* __restrict__ ctx) {
    __shared__ float As[16][68];
    __shared__ float Bs[16][68];
    int b  = blockIdx.z;
    int m0 = blockIdx.y * 64, n0 = blockIdx.x * 64;
    int tid = threadIdx.x;
    int tx = tid & 15, ty = tid >> 4;
    int lr = tid >> 2, lk = (tid & 3) * 4;     // A-tile load mapping
    int bk = tid >> 4, bn = (tid & 15) * 4;    // B-tile load mapping

    const float* Abase = wgt + (size_t)b * TT_ * ST_ + (size_t)(m0 + lr) * ST_ + lk;
    const float* Bbase = enc + (size_t)b * ST_ * H_ + n0 + bn;

    float acc[4][4] = {};
    for (int k0 = 0; k0 < ST_; k0 += 16) {
        float4 av = *(const float4*)(Abase + k0);
        float4 bv = *(const float4*)(Bbase + (size_t)(k0 + bk) * H_);
        __syncthreads();
        As[lk + 0][lr] = av.x; As[lk + 1][lr] = av.y;
        As[lk + 2][lr] = av.z; As[lk + 3][lr] = av.w;
        *(float4*)&Bs[bk][bn] = bv;
        __syncthreads();
#pragma unroll
        for (int kk = 0; kk < 16; ++kk) {
            float4 a  = *(const float4*)&As[kk][ty * 4];
            float4 bb = *(const float4*)&Bs[kk][tx * 4];
            FMA16(a, bb)
        }
    }
#pragma unroll
    for (int i = 0; i < 4; ++i)
#pragma unroll
        for (int jj = 0; jj < 4; ++jj)
            ctx[(size_t)b * TT_ * H_ + (size_t)(m0 + ty * 4 + i) * H_ + (n0 + tx * 4 + jj)] = acc[i][jj];
}

// ---------------------------------------------------------------------------
// K5: out[b,t,o] = (t < trg_len[b]) ? [h|ctx] . fc_W[o] + fc_b[o] : 0
// ---------------------------------------------------------------------------
__global__ __launch_bounds__(256) void k_out(const float* __restrict__ h_all,
                                             const float* __restrict__ ctx,
                                             const float* __restrict__ fc_Wt,
                                             const float* __restrict__ fc_b,
                                             const int* __restrict__ trg_len,
                                             float* __restrict__ out) {
    int tid = threadIdx.x;
    int o = tid & 31;
    int m = blockIdx.x * 8 + (tid >> 5);     // b*TT + t
    int b = m >> 8, t = m & 255;
    const float* xh = h_all + (size_t)m * H_;
    const float* xc = ctx + (size_t)m * H_;
    float acc = (o < O_) ? fc_b[o] : 0.f;
#pragma unroll 4
    for (int k = 0; k < H_; ++k) acc = fmaf(xh[k], fc_Wt[k * 32 + o], acc);
#pragma unroll 4
    for (int k = 0; k < H_; ++k) acc = fmaf(xc[k], fc_Wt[(H_ + k) * 32 + o], acc);
    if (o < O_) {
        float val = (t < trg_len[b]) ? acc : 0.0f;
        out[(size_t)m * O_ + o] = val;
    }
}

// ---------------------------------------------------------------------------
extern "C" void kernel_launch(void* const* d_in, const int* in_sizes, int n_in,
                              void* d_out, int out_size, void* d_ws, size_t ws_size,
                              hipStream_t stream) {
    const int*   trg      = (const int*)d_in[0];
    const int*   trg_len  = (const int*)d_in[1];
    const int*   src_len  = (const int*)d_in[2];
    const float* enc      = (const float*)d_in[3];
    const float* enc_last = (const float*)d_in[4];
    const float* embed    = (const float*)d_in[5];
    const float* W_ih     = (const float*)d_in[6];
    const float* W_hh     = (const float*)d_in[7];
    const float* b_ih     = (const float*)d_in[8];
    const float* b_hh     = (const float*)d_in[9];
    const float* fc_W     = (const float*)d_in[10];
    const float* fc_b     = (const float*)d_in[11];
    float* out = (float*)d_out;

    char* ws = (char*)d_ws;
    float* giV   = (float*)ws;  ws += (size_t)V_ * G3_ * 4;            // 192 KB
    float* fc_Wt = (float*)ws;  ws += (size_t)1024 * 32 * 4;           // 128 KB
    float* h_all = (float*)ws;  ws += (size_t)B_ * TT_ * H_ * 4;       // 32 MB
    float* wgt   = (float*)ws;  ws += (size_t)B_ * TT_ * ST_ * 4;      // 64 MB
    float* ctx   = (float*)ws;  ws += (size_t)B_ * TT_ * H_ * 4;       // 32 MB
    unsigned* cnt = (unsigned*)ws;
    ws += (size_t)TT_ * NGRP_ * CSTRIDE_ * 4;                          // 512 KB

    k_giv<<<192, 256, 0, stream>>>(embed, W_ih, b_ih, giV);
    k_fcw_t<<<128, 256, 0, stream>>>(fc_W, fc_Wt, cnt);

    // ---- persistent GRU (co-residency via cooperative launch; own sync) ----
    void* kargs[7];
    kargs[0] = (void*)&enc_last;
    kargs[1] = (void*)&giV;
    kargs[2] = (void*)&trg;
    kargs[3] = (void*)&W_hh;
    kargs[4] = (void*)&b_hh;
    kargs[5] = (void*)&h_all;
    kargs[6] = (void*)&cnt;
    hipError_t ce = hipLaunchCooperativeKernel((const void*)k_gru_persist,
                                               dim3(512), dim3(256),
                                               kargs, 0, stream);
    if (ce != hipSuccess) {
        (void)hipGetLastError();   // clear error; fall back to per-step loop
        for (int t = 0; t < TT_; ++t) {
            const float* hp = t ? (h_all + (size_t)(t - 1) * H_) : enc_last;
            int stride = t ? TT_ * H_ : H_;
            k_gru_step<<<512, 256, 0, stream>>>(hp, stride, giV, trg, W_hh, b_hh, h_all, t);
        }
    }

    k_scores<<<dim3(ST_ / 64, TT_ / 64, B_), 256, 0, stream>>>(h_all, enc, wgt);
    k_softmax<<<B_ * TT_, 256, 0, stream>>>(wgt, src_len);
    k_ctx<<<dim3(H_ / 64, TT_ / 64, B_), 256, 0, stream>>>(wgt, enc, ctx);
    k_out<<<B_ * TT_ / 8, 256, 0, stream>>>(h_all, ctx, fc_Wt, fc_b, trg_len, out);
}

// Round 4
// 3389.687 us; speedup vs baseline: 1.4553x; 1.4553x over previous
//
#include <hip/hip_runtime.h>
#include <math.h>

// Problem constants (B, ST, TT, H, E, V, O) = (64, 1024, 256, 512, 512, 32, 31)
#define B_   64
#define ST_  1024
#define TT_  256
#define H_   512
#define E_   512
#define V_   32
#define O_   31
#define G3_  1536   // 3*H
#define NGRP_ 8     // batch groups, each covers 8 batches
#define NJC_  32    // WGs per group (each owns 16 j's)

// ---------------------------------------------------------------------------
// coherent-point access helpers: sc0 sc1 = write-through / L2-bypass on gfx950
// ---------------------------------------------------------------------------
__device__ __forceinline__ void load2_sc(const float* p0, const float* p1,
                                         float4& r0, float4& r1) {
    asm volatile(
        "global_load_dwordx4 %0, %2, off sc0 sc1\n\t"
        "global_load_dwordx4 %1, %3, off sc0 sc1\n\t"
        "s_waitcnt vmcnt(0)"
        : "=&v"(r0), "=&v"(r1)
        : "v"(p0), "v"(p1)
        : "memory");
}

__device__ __forceinline__ void store_sc(float* p, float v) {
    asm volatile("global_store_dword %0, %1, off sc0 sc1"
                 :: "v"(p), "v"(v) : "memory");
}

__device__ __forceinline__ void store_sc_u32(unsigned* p, unsigned v) {
    asm volatile("global_store_dword %0, %1, off sc0 sc1"
                 :: "v"(p), "v"(v) : "memory");
}

__device__ __forceinline__ unsigned load_sc_u32(const unsigned* p) {
    unsigned r;
    asm volatile("global_load_dword %0, %1, off sc0 sc1\n\t"
                 "s_waitcnt vmcnt(0)"
                 : "=v"(r) : "v"(p) : "memory");
    return r;
}

// ---------------------------------------------------------------------------
// K0a: giV[v, n] = sum_k embed[v,k] * W_ih[n,k] + b_ih[n]   (32 x 1536)
// ---------------------------------------------------------------------------
__global__ __launch_bounds__(256) void k_giv(const float* __restrict__ embed,
                                             const float* __restrict__ W_ih,
                                             const float* __restrict__ b_ih,
                                             float* __restrict__ giV) {
    int idx = blockIdx.x * 256 + threadIdx.x;       // 0 .. 49151
    if (idx >= V_ * G3_) return;
    int v = idx / G3_, n = idx % G3_;
    const float4* e4 = (const float4*)(embed + v * E_);
    const float4* w4 = (const float4*)(W_ih + (size_t)n * E_);
    float acc = 0.f;
#pragma unroll 4
    for (int k = 0; k < E_ / 4; ++k) {
        float4 a = e4[k], b = w4[k];
        acc += a.x * b.x + a.y * b.y + a.z * b.z + a.w * b.w;
    }
    giV[idx] = acc + b_ih[n];
}

// ---------------------------------------------------------------------------
// K0b: transpose fc_W -> fc_Wt (1024 x 32) and zero the 65536 flag words
// ---------------------------------------------------------------------------
__global__ __launch_bounds__(256) void k_fcw_t(const float* __restrict__ fc_W,
                                               float* __restrict__ fc_Wt,
                                               unsigned* __restrict__ flags) {
    int idx = blockIdx.x * 256 + threadIdx.x;       // 0 .. 32767
    int k = idx >> 5, o = idx & 31;
    fc_Wt[idx] = (o < O_) ? fc_W[(size_t)o * 1024 + k] : 0.f;
    flags[idx] = 0u;
    flags[idx + 32768] = 0u;
}

// ---------------------------------------------------------------------------
// K1p: persistent GRU, all 256 steps in one dispatch.
// Grid = 256 WGs (bc=8 groups x jc=32) x 512 thr (co-resident, 8 waves/CU).
// Each WG owns 16 j's x 8 batches. Thread = (bl=tid&7, ks=(tid>>3)&3,
// jl=tid>>5) — identical per-j arithmetic (4x128 K-split, shfl_xor(8|16))
// to the verified kernel => bit-identical h.
// Sync per step: single-writer flag words (no atomics, no RMW serialization):
// producer stores flags[t][bc][jc]=1 after its h stores ack; consumers poll
// all 32 group flags with ONE wave-wide 32-lane sc1 load per poll round.
// h exchange via sc0/sc1 through the device-coherent point (fresh addresses
// each t, so no stale-cache hazards).
// ---------------------------------------------------------------------------
__global__ __launch_bounds__(512, 1) void k_gru_persist(
        const float* __restrict__ h0,
        const float* __restrict__ giV,
        const int* __restrict__ trg,
        const float* __restrict__ W_hh,
        const float* __restrict__ b_hh,
        float* __restrict__ h_all,
        unsigned* __restrict__ flags) {
    __shared__ float hsf[4224];   // 8 rows x 4 ks x 132 floats (padded)

    int tid = threadIdx.x;
    int jc = blockIdx.x & 31, bc = blockIdx.x >> 5;
    int b0 = bc * 8, j0 = jc * 16;

    int bl = tid & 7;                            // batch within block
    int ks = (tid >> 3) & 3;                     // K-split id (128 each)
    int jl = tid >> 5;                           // j within block (0..15)
    int j  = j0 + jl;
    int k0 = ks * 128;

    // loop-invariant W pointers (global; L2-resident after first step)
    const float4* w0 = (const float4*)(W_hh + (size_t)(j         ) * H_ + k0);
    const float4* w1 = (const float4*)(W_hh + (size_t)(j +   H_  ) * H_ + k0);
    const float4* w2 = (const float4*)(W_hh + (size_t)(j + 2 * H_) * H_ + k0);
    const float4* h4 = (const float4*)&hsf[bl * 528 + ks * 132];

    float bhr = b_hh[j], bhz = b_hh[H_ + j], bhn = b_hh[2 * H_ + j];

    // staging geometry: 1024 float4 pieces, 512 threads -> 2 rows each
    int k4s = tid & 127, rw = tid >> 7;          // rw in 0..3; rows rw, rw+4
    int lds_off = (k4s >> 5) * 132 + (k4s & 31) * 4;

    for (int t = 0; t < TT_; ++t) {
        if (t == 0) {
            float4 v0 = *(const float4*)(h0 + (size_t)(b0 + rw    ) * H_ + k4s * 4);
            float4 v1 = *(const float4*)(h0 + (size_t)(b0 + rw + 4) * H_ + k4s * 4);
            *(float4*)&hsf[(rw    ) * 528 + lds_off] = v0;
            *(float4*)&hsf[(rw + 4) * 528 + lds_off] = v1;
        } else {
            // wait for all 32 producers of group bc at step t-1
            if (tid < 64) {
                const unsigned* fp = flags +
                    ((size_t)(t - 1) * NGRP_ + bc) * NJC_ + (tid & 31);
                int guard = 0;
                while (load_sc_u32(fp) == 0u) {
                    __builtin_amdgcn_s_sleep(1);
                    if (++guard > (1 << 22)) break;   // safety valve
                }
            }
            __syncthreads();
            const float* pb = h_all + (size_t)(t - 1) * H_ + (size_t)k4s * 4;
            float4 r0v, r1v;
            load2_sc(pb + (size_t)(b0 + rw    ) * (TT_ * H_),
                     pb + (size_t)(b0 + rw + 4) * (TT_ * H_), r0v, r1v);
            *(float4*)&hsf[(rw    ) * 528 + lds_off] = r0v;
            *(float4*)&hsf[(rw + 4) * 528 + lds_off] = r1v;
        }
        __syncthreads();

        float sr = 0.f, sz = 0.f, sn = 0.f;
#pragma unroll 8
        for (int k = 0; k < 32; ++k) {
            float4 hv = h4[k];
            float4 a = w0[k], c = w1[k], d = w2[k];
            sr += hv.x * a.x + hv.y * a.y + hv.z * a.z + hv.w * a.w;
            sz += hv.x * c.x + hv.y * c.y + hv.z * c.z + hv.w * c.w;
            sn += hv.x * d.x + hv.y * d.y + hv.z * d.z + hv.w * d.w;
        }
        sr += __shfl_xor(sr, 8);  sr += __shfl_xor(sr, 16);
        sz += __shfl_xor(sz, 8);  sz += __shfl_xor(sz, 16);
        sn += __shfl_xor(sn, 8);  sn += __shfl_xor(sn, 16);

        if (ks == 0) {
            int b = b0 + bl;
            int tok = trg[(size_t)b * TT_ + t];
            const float* gv = giV + (size_t)tok * G3_;
            float r = 1.f / (1.f + expf(-(gv[j] + sr + bhr)));
            float z = 1.f / (1.f + expf(-(gv[H_ + j] + sz + bhz)));
            float n = tanhf(gv[2 * H_ + j] + r * (sn + bhn));
            float hpv = hsf[bl * 528 + (j >> 7) * 132 + (j & 127)];
            store_sc(h_all + (size_t)b * TT_ * H_ + (size_t)t * H_ + j,
                     (1.f - z) * n + z * hpv);
        }

        // drain this wave's write-through stores to the coherent point
        asm volatile("s_waitcnt vmcnt(0)" ::: "memory");
        __syncthreads();   // whole WG's h[t] is at the coherent point

        if (t < TT_ - 1 && tid == 0) {
            store_sc_u32(flags + ((size_t)t * NGRP_ + bc) * NJC_ + jc, 1u);
        }
        // next iteration's poll + __syncthreads provides the step ordering
    }
}

// ---------------------------------------------------------------------------
// K1 (fallback): one GRU step per launch — used only if cooperative launch
// is unavailable. Identical math.
// ---------------------------------------------------------------------------
__global__ __launch_bounds__(256) void k_gru_step(const float* __restrict__ h_prev,
                                                  int hp_stride,
                                                  const float* __restrict__ giV,
                                                  const int* __restrict__ trg,
                                                  const float* __restrict__ W_hh,
                                                  const float* __restrict__ b_hh,
                                                  float* __restrict__ h_all,
                                                  int t) {
    __shared__ float hs[8][520];
    int tid = threadIdx.x;
    int jc = blockIdx.x & 63, bc = blockIdx.x >> 6;
    int b0 = bc * 8;

#pragma unroll
    for (int i = 0; i < 4; ++i) {
        int fi = tid + i * 256;
        int bl2 = fi >> 7, k4 = fi & 127;
        float4 v = *(const float4*)(h_prev + (size_t)(b0 + bl2) * hp_stride + k4 * 4);
        *(float4*)&hs[bl2][k4 * 4] = v;
    }
    __syncthreads();

    int bl = tid & 7;
    int ks = (tid >> 3) & 3;
    int jl = tid >> 5;
    int j  = jc * 8 + jl;
    int k0 = ks * 128;

    const float4* w0 = (const float4*)(W_hh + (size_t)(j         ) * H_ + k0);
    const float4* w1 = (const float4*)(W_hh + (size_t)(j +   H_  ) * H_ + k0);
    const float4* w2 = (const float4*)(W_hh + (size_t)(j + 2 * H_) * H_ + k0);
    const float4* h4 = (const float4*)&hs[bl][k0];

    float sr = 0.f, sz = 0.f, sn = 0.f;
#pragma unroll 8
    for (int k = 0; k < 32; ++k) {
        float4 hv = h4[k];
        float4 a = w0[k], c = w1[k], d = w2[k];
        sr += hv.x * a.x + hv.y * a.y + hv.z * a.z + hv.w * a.w;
        sz += hv.x * c.x + hv.y * c.y + hv.z * c.z + hv.w * c.w;
        sn += hv.x * d.x + hv.y * d.y + hv.z * d.z + hv.w * d.w;
    }
    sr += __shfl_xor(sr, 8);  sr += __shfl_xor(sr, 16);
    sz += __shfl_xor(sz, 8);  sz += __shfl_xor(sz, 16);
    sn += __shfl_xor(sn, 8);  sn += __shfl_xor(sn, 16);

    if (ks == 0) {
        int b = b0 + bl;
        int tok = trg[(size_t)b * TT_ + t];
        const float* gv = giV + (size_t)tok * G3_;
        float gh_r = sr + b_hh[j];
        float gh_z = sz + b_hh[H_ + j];
        float gh_n = sn + b_hh[2 * H_ + j];
        float r = 1.f / (1.f + expf(-(gv[j] + gh_r)));
        float z = 1.f / (1.f + expf(-(gv[H_ + j] + gh_z)));
        float n = tanhf(gv[2 * H_ + j] + r * gh_n);
        float hp = hs[bl][j];
        h_all[(size_t)b * TT_ * H_ + (size_t)t * H_ + j] = (1.f - z) * n + z * hp;
    }
}

// FMA micro-kernel helper for the 4x4 register tiles
#define FMA16(a, bb)                                                     \
    acc[0][0] = fmaf(a.x, bb.x, acc[0][0]);                              \
    acc[0][1] = fmaf(a.x, bb.y, acc[0][1]);                              \
    acc[0][2] = fmaf(a.x, bb.z, acc[0][2]);                              \
    acc[0][3] = fmaf(a.x, bb.w, acc[0][3]);                              \
    acc[1][0] = fmaf(a.y, bb.x, acc[1][0]);                              \
    acc[1][1] = fmaf(a.y, bb.y, acc[1][1]);                              \
    acc[1][2] = fmaf(a.y, bb.z, acc[1][2]);                              \
    acc[1][3] = fmaf(a.y, bb.w, acc[1][3]);                              \
    acc[2][0] = fmaf(a.z, bb.x, acc[2][0]);                              \
    acc[2][1] = fmaf(a.z, bb.y, acc[2][1]);                              \
    acc[2][2] = fmaf(a.z, bb.z, acc[2][2]);                              \
    acc[2][3] = fmaf(a.z, bb.w, acc[2][3]);                              \
    acc[3][0] = fmaf(a.w, bb.x, acc[3][0]);                              \
    acc[3][1] = fmaf(a.w, bb.y, acc[3][1]);                              \
    acc[3][2] = fmaf(a.w, bb.z, acc[3][2]);                              \
    acc[3][3] = fmaf(a.w, bb.w, acc[3][3]);

// ---------------------------------------------------------------------------
// K2: scores[b, t, s] = sum_k h_all[b,t,k] * enc[b,s,k]   (NT GEMM per batch)
// ---------------------------------------------------------------------------
__global__ __launch_bounds__(256) void k_scores(const float* __restrict__ h_all,
                                                const float* __restrict__ enc,
                                                float* __restrict__ wgt) {
    __shared__ float As[16][68];
    __shared__ float Bs[16][68];
    int b  = blockIdx.z;
    int m0 = blockIdx.y * 64, n0 = blockIdx.x * 64;
    int tid = threadIdx.x;
    int tx = tid & 15, ty = tid >> 4;
    int lr = tid >> 2, lk = (tid & 3) * 4;

    const float* Abase = h_all + (size_t)b * TT_ * H_ + (size_t)(m0 + lr) * H_ + lk;
    const float* Bbase = enc   + (size_t)b * ST_ * H_ + (size_t)(n0 + lr) * H_ + lk;

    float acc[4][4] = {};
    for (int k0 = 0; k0 < H_; k0 += 16) {
        float4 av = *(const float4*)(Abase + k0);
        float4 bv = *(const float4*)(Bbase + k0);
        __syncthreads();
        As[lk + 0][lr] = av.x; As[lk + 1][lr] = av.y;
        As[lk + 2][lr] = av.z; As[lk + 3][lr] = av.w;
        Bs[lk + 0][lr] = bv.x; Bs[lk + 1][lr] = bv.y;
        Bs[lk + 2][lr] = bv.z; Bs[lk + 3][lr] = bv.w;
        __syncthreads();
#pragma unroll
        for (int kk = 0; kk < 16; ++kk) {
            float4 a  = *(const float4*)&As[kk][ty * 4];
            float4 bb = *(const float4*)&Bs[kk][tx * 4];
            FMA16(a, bb)
        }
    }
#pragma unroll
    for (int i = 0; i < 4; ++i)
#pragma unroll
        for (int jj = 0; jj < 4; ++jj)
            wgt[(size_t)b * TT_ * ST_ + (size_t)(m0 + ty * 4 + i) * ST_ + (n0 + tx * 4 + jj)] = acc[i][jj];
}

// ---------------------------------------------------------------------------
// K3: masked softmax over s (row length 1024). One block per (b, t) row.
// ---------------------------------------------------------------------------
__global__ __launch_bounds__(256) void k_softmax(float* __restrict__ wgt,
                                                 const int* __restrict__ source_len) {
    __shared__ float red[8];
    int row = blockIdx.x;            // b*TT + t
    int b = row >> 8;
    int slen = source_len[b];
    float* W = wgt + (size_t)row * ST_;
    int tid = threadIdx.x;

    float v[4];
    float mx = -3.0e38f;
#pragma unroll
    for (int i = 0; i < 4; ++i) {
        int s = tid + i * 256;
        v[i] = (s < slen) ? W[s] : -1e9f;
        mx = fmaxf(mx, v[i]);
    }
#pragma unroll
    for (int off = 32; off; off >>= 1) mx = fmaxf(mx, __shfl_xor(mx, off));
    int wv = tid >> 6;
    if ((tid & 63) == 0) red[wv] = mx;
    __syncthreads();
    mx = fmaxf(fmaxf(red[0], red[1]), fmaxf(red[2], red[3]));

    float sm = 0.f;
#pragma unroll
    for (int i = 0; i < 4; ++i) {
        v[i] = expf(v[i] - mx);
        sm += v[i];
    }
#pragma unroll
    for (int off = 32; off; off >>= 1) sm += __shfl_xor(sm, off);
    if ((tid & 63) == 0) red[4 + wv] = sm;
    __syncthreads();
    sm = red[4] + red[5] + red[6] + red[7];
    float inv = 1.f / sm;
#pragma unroll
    for (int i = 0; i < 4; ++i)
        W[tid + i * 256] = v[i] * inv;
}

// ---------------------------------------------------------------------------
// K4: ctx[b, t, n] = sum_s wgt[b,t,s] * enc[b,s,n]   (NN GEMM per batch)
// ---------------------------------------------------------------------------
__global__ __launch_bounds__(256) void k_ctx(const float* __restrict__ wgt,
                                             const float* __restrict__ enc,
                                             float* __restrict__ ctx) {
    __shared__ float As[16][68];
    __shared__ float Bs[16][68];
    int b  = blockIdx.z;
    int m0 = blockIdx.y * 64, n0 = blockIdx.x * 64;
    int tid = threadIdx.x;
    int tx = tid & 15, ty = tid >> 4;
    int lr = tid >> 2, lk = (tid & 3) * 4;     // A-tile load mapping
    int bk = tid >> 4, bn = (tid & 15) * 4;    // B-tile load mapping

    const float* Abase = wgt + (size_t)b * TT_ * ST_ + (size_t)(m0 + lr) * ST_ + lk;
    const float* Bbase = enc + (size_t)b * ST_ * H_ + n0 + bn;

    float acc[4][4] = {};
    for (int k0 = 0; k0 < ST_; k0 += 16) {
        float4 av = *(const float4*)(Abase + k0);
        float4 bv = *(const float4*)(Bbase + (size_t)(k0 + bk) * H_);
        __syncthreads();
        As[lk + 0][lr] = av.x; As[lk + 1][lr] = av.y;
        As[lk + 2][lr] = av.z; As[lk + 3][lr] = av.w;
        *(float4*)&Bs[bk][bn] = bv;
        __syncthreads();
#pragma unroll
        for (int kk = 0; kk < 16; ++kk) {
            float4 a  = *(const float4*)&As[kk][ty * 4];
            float4 bb = *(const float4*)&Bs[kk][tx * 4];
            FMA16(a, bb)
        }
    }
#pragma unroll
    for (int i = 0; i < 4; ++i)
#pragma unroll
        for (int jj = 0; jj < 4; ++jj)
            ctx[(size_t)b * TT_ * H_ + (size_t)(m0 + ty * 4 + i) * H_ + (n0 + tx * 4 + jj)] = acc[i][jj];
}

// ---------------------------------------------------------------------------
// K5: out[b,t,o] = (t < trg_len[b]) ? [h|ctx] . fc_W[o] + fc_b[o] : 0
// ---------------------------------------------------------------------------
__global__ __launch_bounds__(256) void k_out(const float* __restrict__ h_all,
                                             const float* __restrict__ ctx,
                                             const float* __restrict__ fc_Wt,
                                             const float* __restrict__ fc_b,
                                             const int* __restrict__ trg_len,
                                             float* __restrict__ out) {
    int tid = threadIdx.x;
    int o = tid & 31;
    int m = blockIdx.x * 8 + (tid >> 5);     // b*TT + t
    int b = m >> 8, t = m & 255;
    const float* xh = h_all + (size_t)m * H_;
    const float* xc = ctx + (size_t)m * H_;
    float acc = (o < O_) ? fc_b[o] : 0.f;
#pragma unroll 4
    for (int k = 0; k < H_; ++k) acc = fmaf(xh[k], fc_Wt[k * 32 + o], acc);
#pragma unroll 4
    for (int k = 0; k < H_; ++k) acc = fmaf(xc[k], fc_Wt[(H_ + k) * 32 + o], acc);
    if (o < O_) {
        float val = (t < trg_len[b]) ? acc : 0.0f;
        out[(size_t)m * O_ + o] = val;
    }
}

// ---------------------------------------------------------------------------
extern "C" void kernel_launch(void* const* d_in, const int* in_sizes, int n_in,
                              void* d_out, int out_size, void* d_ws, size_t ws_size,
                              hipStream_t stream) {
    const int*   trg      = (const int*)d_in[0];
    const int*   trg_len  = (const int*)d_in[1];
    const int*   src_len  = (const int*)d_in[2];
    const float* enc      = (const float*)d_in[3];
    const float* enc_last = (const float*)d_in[4];
    const float* embed    = (const float*)d_in[5];
    const float* W_ih     = (const float*)d_in[6];
    const float* W_hh     = (const float*)d_in[7];
    const float* b_ih     = (const float*)d_in[8];
    const float* b_hh     = (const float*)d_in[9];
    const float* fc_W     = (const float*)d_in[10];
    const float* fc_b     = (const float*)d_in[11];
    float* out = (float*)d_out;

    char* ws = (char*)d_ws;
    float* giV   = (float*)ws;  ws += (size_t)V_ * G3_ * 4;            // 192 KB
    float* fc_Wt = (float*)ws;  ws += (size_t)1024 * 32 * 4;           // 128 KB
    float* h_all = (float*)ws;  ws += (size_t)B_ * TT_ * H_ * 4;       // 32 MB
    float* wgt   = (float*)ws;  ws += (size_t)B_ * TT_ * ST_ * 4;      // 64 MB
    float* ctx   = (float*)ws;  ws += (size_t)B_ * TT_ * H_ * 4;       // 32 MB
    unsigned* flags = (unsigned*)ws;
    ws += (size_t)TT_ * NGRP_ * NJC_ * 4;                              // 256 KB

    k_giv<<<192, 256, 0, stream>>>(embed, W_ih, b_ih, giV);
    k_fcw_t<<<128, 256, 0, stream>>>(fc_W, fc_Wt, flags);

    // ---- persistent GRU (co-residency via cooperative launch; flag sync) ----
    void* kargs[7];
    kargs[0] = (void*)&enc_last;
    kargs[1] = (void*)&giV;
    kargs[2] = (void*)&trg;
    kargs[3] = (void*)&W_hh;
    kargs[4] = (void*)&b_hh;
    kargs[5] = (void*)&h_all;
    kargs[6] = (void*)&flags;
    hipError_t ce = hipLaunchCooperativeKernel((const void*)k_gru_persist,
                                               dim3(256), dim3(512),
                                               kargs, 0, stream);
    if (ce != hipSuccess) {
        (void)hipGetLastError();   // clear error; fall back to per-step loop
        for (int t = 0; t < TT_; ++t) {
            const float* hp = t ? (h_all + (size_t)(t - 1) * H_) : enc_last;
            int stride = t ? TT_ * H_ : H_;
            k_gru_step<<<512, 256, 0, stream>>>(hp, stride, giV, trg, W_hh, b_hh, h_all, t);
        }
    }

    k_scores<<<dim3(ST_ / 64, TT_ / 64, B_), 256, 0, stream>>>(h_all, enc, wgt);
    k_softmax<<<B_ * TT_, 256, 0, stream>>>(wgt, src_len);
    k_ctx<<<dim3(H_ / 64, TT_ / 64, B_), 256, 0, stream>>>(wgt, enc, ctx);
    k_out<<<B_ * TT_ / 8, 256, 0, stream>>>(h_all, ctx, fc_Wt, fc_b, trg_len, out);
}

// Round 7
// 2947.096 us; speedup vs baseline: 1.6738x; 1.1502x over previous
//
#include <hip/hip_runtime.h>
#include <math.h>

// Problem constants (B, ST, TT, H, E, V, O) = (64, 1024, 256, 512, 512, 32, 31)
#define B_   64
#define ST_  1024
#define TT_  256
#define H_   512
#define E_   512
#define V_   32
#define O_   31
#define G3_  1536   // 3*H
#define NGRP_ 8     // batch groups, each covers 8 batches
#define NJC_  32    // WGs per group (each owns 16 j's)

typedef float f32x4 __attribute__((ext_vector_type(4)));

// ---------------------------------------------------------------------------
// coherent-point access helpers: sc0 sc1 = write-through / L2-bypass on gfx950
// ---------------------------------------------------------------------------
__device__ __forceinline__ void load2_sc(const float* p0, const float* p1,
                                         float4& r0, float4& r1) {
    asm volatile(
        "global_load_dwordx4 %0, %2, off sc0 sc1\n\t"
        "global_load_dwordx4 %1, %3, off sc0 sc1\n\t"
        "s_waitcnt vmcnt(0)"
        : "=&v"(r0), "=&v"(r1)
        : "v"(p0), "v"(p1)
        : "memory");
}

__device__ __forceinline__ void store_sc4(float* p, float x, float y,
                                          float z, float w) {
    f32x4 v;
    v.x = x; v.y = y; v.z = z; v.w = w;
    asm volatile("global_store_dwordx4 %0, %1, off sc0 sc1"
                 :: "v"(p), "v"(v) : "memory");
}

__device__ __forceinline__ void store_sc_u32(unsigned* p, unsigned v) {
    asm volatile("global_store_dword %0, %1, off sc0 sc1"
                 :: "v"(p), "v"(v) : "memory");
}

__device__ __forceinline__ unsigned load_sc_u32(const unsigned* p) {
    unsigned r;
    asm volatile("global_load_dword %0, %1, off sc0 sc1\n\t"
                 "s_waitcnt vmcnt(0)"
                 : "=v"(r) : "v"(p) : "memory");
    return r;
}

// ---------------------------------------------------------------------------
// K0a: giV[v, n] = sum_k embed[v,k] * W_ih[n,k] + b_ih[n]   (32 x 1536)
// ---------------------------------------------------------------------------
__global__ __launch_bounds__(256) void k_giv(const float* __restrict__ embed,
                                             const float* __restrict__ W_ih,
                                             const float* __restrict__ b_ih,
                                             float* __restrict__ giV) {
    int idx = blockIdx.x * 256 + threadIdx.x;       // 0 .. 49151
    if (idx >= V_ * G3_) return;
    int v = idx / G3_, n = idx % G3_;
    const float4* e4 = (const float4*)(embed + v * E_);
    const float4* w4 = (const float4*)(W_ih + (size_t)n * E_);
    float acc = 0.f;
#pragma unroll 4
    for (int k = 0; k < E_ / 4; ++k) {
        float4 a = e4[k], b = w4[k];
        acc += a.x * b.x + a.y * b.y + a.z * b.z + a.w * b.w;
    }
    giV[idx] = acc + b_ih[n];
}

// ---------------------------------------------------------------------------
// K0b: transpose fc_W -> fc_Wt (1024 x 32) and zero the 65536 flag words
// ---------------------------------------------------------------------------
__global__ __launch_bounds__(256) void k_fcw_t(const float* __restrict__ fc_W,
                                               float* __restrict__ fc_Wt,
                                               unsigned* __restrict__ flags) {
    int idx = blockIdx.x * 256 + threadIdx.x;       // 0 .. 32767
    int k = idx >> 5, o = idx & 31;
    fc_Wt[idx] = (o < O_) ? fc_W[(size_t)o * 1024 + k] : 0.f;
    flags[idx] = 0u;
    flags[idx + 32768] = 0u;
}

// FMA group helper: accumulate one float4 (order identical to the verified
// scalar expression: x, y, z, w ascending k)
#define ACC3(hv, a, c, d)                                                \
    sr += hv.x * a.x + hv.y * a.y + hv.z * a.z + hv.w * a.w;             \
    sz += hv.x * c.x + hv.y * c.y + hv.z * c.z + hv.w * c.w;             \
    sn += hv.x * d.x + hv.y * d.y + hv.z * d.z + hv.w * d.w;

// ---------------------------------------------------------------------------
// K1p: persistent GRU, all 256 steps in one dispatch.
// Grid = 256 WGs (bc=8 groups x jc=32) x 512 thr (co-resident, 1 WG/CU).
// Thread = (bl=tid&7, ks=(tid>>3)&3, jl=tid>>5): 4x128 K-split +
// shfl_xor(8|16) reduce — bit-identical arithmetic to the verified kernel.
// Inner loop: explicit 2-buffer register pipeline (chunks of 4 float4 per
// gate) to keep ~28 loads in flight (VGPR-starved at 64 in R4).
// h stores: gate results gathered in LDS, written as 32 dwordx4 sc0/sc1
// transactions per WG (was 128 scalar dwords -> 4x sector-RMW).
// Sync per step: single-writer flag words; consumers poll 32 flags with one
// wave-wide sc1 load per round.
// ---------------------------------------------------------------------------
__global__ __launch_bounds__(512, 1) void k_gru_persist(
        const float* __restrict__ h0,
        const float* __restrict__ giV,
        const int* __restrict__ trg,
        const float* __restrict__ W_hh,
        const float* __restrict__ b_hh,
        float* __restrict__ h_all,
        unsigned* __restrict__ flags) {
    __shared__ float hsf[4224];    // 8 rows x 4 ks x 132 floats (padded)
    __shared__ float hnew[160];    // 8 rows x 20 (gate-result gather buffer)

    int tid = threadIdx.x;
    int jc = blockIdx.x & 31, bc = blockIdx.x >> 5;
    int b0 = bc * 8, j0 = jc * 16;

    int bl = tid & 7;                            // batch within block
    int ks = (tid >> 3) & 3;                     // K-split id (128 each)
    int jl = tid >> 5;                           // j within block (0..15)
    int j  = j0 + jl;
    int k0 = ks * 128;

    // loop-invariant W pointers (global; L2-resident after first step)
    const float4* w0 = (const float4*)(W_hh + (size_t)(j         ) * H_ + k0);
    const float4* w1 = (const float4*)(W_hh + (size_t)(j +   H_  ) * H_ + k0);
    const float4* w2 = (const float4*)(W_hh + (size_t)(j + 2 * H_) * H_ + k0);
    const float4* h4 = (const float4*)&hsf[bl * 528 + ks * 132];

    float bhr = b_hh[j], bhz = b_hh[H_ + j], bhn = b_hh[2 * H_ + j];

    // staging geometry: 1024 float4 pieces, 512 threads -> 2 rows each
    int k4s = tid & 127, rw = tid >> 7;          // rw in 0..3; rows rw, rw+4
    int lds_off = (k4s >> 5) * 132 + (k4s & 31) * 4;

    for (int t = 0; t < TT_; ++t) {
        // W chunk-0 prefetch: invariant addresses, issue before the wait
        float4 A0[4], C0[4], D0[4], A1[4], C1[4], D1[4], Hq0[4], Hq1[4];
#pragma unroll
        for (int u = 0; u < 4; ++u) { A0[u] = w0[u]; C0[u] = w1[u]; D0[u] = w2[u]; }

        if (t == 0) {
            float4 v0 = *(const float4*)(h0 + (size_t)(b0 + rw    ) * H_ + k4s * 4);
            float4 v1 = *(const float4*)(h0 + (size_t)(b0 + rw + 4) * H_ + k4s * 4);
            *(float4*)&hsf[(rw    ) * 528 + lds_off] = v0;
            *(float4*)&hsf[(rw + 4) * 528 + lds_off] = v1;
        } else {
            // wait for all 32 producers of group bc at step t-1
            if (tid < 64) {
                const unsigned* fp = flags +
                    ((size_t)(t - 1) * NGRP_ + bc) * NJC_ + (tid & 31);
                int guard = 0;
                while (load_sc_u32(fp) == 0u) {
                    __builtin_amdgcn_s_sleep(1);
                    if (++guard > (1 << 22)) break;   // safety valve
                }
            }
            __syncthreads();
            const float* pb = h_all + (size_t)(t - 1) * H_ + (size_t)k4s * 4;
            float4 r0v, r1v;
            load2_sc(pb + (size_t)(b0 + rw    ) * (TT_ * H_),
                     pb + (size_t)(b0 + rw + 4) * (TT_ * H_), r0v, r1v);
            *(float4*)&hsf[(rw    ) * 528 + lds_off] = r0v;
            *(float4*)&hsf[(rw + 4) * 528 + lds_off] = r1v;
        }
        __syncthreads();

        float sr = 0.f, sz = 0.f, sn = 0.f;
#pragma unroll
        for (int u = 0; u < 4; ++u) Hq0[u] = h4[u];

        // 8 chunks of 4 float4 (k = 0..31), 2-buffer software pipeline.
        // Accumulation order identical to the original k-ascending loop.
#pragma unroll
        for (int c = 0; c < 8; c += 2) {
#pragma unroll
            for (int u = 0; u < 4; ++u) {
                int k1 = (c + 1) * 4 + u;
                A1[u] = w0[k1]; C1[u] = w1[k1]; D1[u] = w2[k1]; Hq1[u] = h4[k1];
            }
#pragma unroll
            for (int u = 0; u < 4; ++u) {
                float4 hv = Hq0[u], a = A0[u], cc = C0[u], d = D0[u];
                ACC3(hv, a, cc, d)
            }
            if (c + 2 < 8) {
#pragma unroll
                for (int u = 0; u < 4; ++u) {
                    int k2 = (c + 2) * 4 + u;
                    A0[u] = w0[k2]; C0[u] = w1[k2]; D0[u] = w2[k2]; Hq0[u] = h4[k2];
                }
            }
#pragma unroll
            for (int u = 0; u < 4; ++u) {
                float4 hv = Hq1[u], a = A1[u], cc = C1[u], d = D1[u];
                ACC3(hv, a, cc, d)
            }
        }
        sr += __shfl_xor(sr, 8);  sr += __shfl_xor(sr, 16);
        sz += __shfl_xor(sz, 8);  sz += __shfl_xor(sz, 16);
        sn += __shfl_xor(sn, 8);  sn += __shfl_xor(sn, 16);

        if (ks == 0) {
            int b = b0 + bl;
            int tok = trg[(size_t)b * TT_ + t];
            const float* gv = giV + (size_t)tok * G3_;
            float r = 1.f / (1.f + expf(-(gv[j] + sr + bhr)));
            float z = 1.f / (1.f + expf(-(gv[H_ + j] + sz + bhz)));
            float n = tanhf(gv[2 * H_ + j] + r * (sn + bhn));
            float hpv = hsf[bl * 528 + (j >> 7) * 132 + (j & 127)];
            hnew[bl * 20 + jl] = (1.f - z) * n + z * hpv;
        }
        __syncthreads();

        // coalesced h[t] write: 32 x dwordx4 per WG (was 128 scalar dwords)
        if (tid < 32) {
            int gb = tid & 7, q = tid >> 3;
            const float* hp4 = &hnew[gb * 20 + q * 4];
            store_sc4(h_all + (size_t)(b0 + gb) * TT_ * H_ + (size_t)t * H_ +
                      j0 + q * 4, hp4[0], hp4[1], hp4[2], hp4[3]);
        }
        asm volatile("s_waitcnt vmcnt(0)" ::: "memory");
        __syncthreads();   // whole WG's h[t] is at the coherent point

        if (t < TT_ - 1 && tid == 0) {
            store_sc_u32(flags + ((size_t)t * NGRP_ + bc) * NJC_ + jc, 1u);
        }
        // next iteration's poll + __syncthreads provides the step ordering
    }
}

// ---------------------------------------------------------------------------
// K1 (fallback): one GRU step per launch — used only if cooperative launch
// is unavailable. Identical math.
// ---------------------------------------------------------------------------
__global__ __launch_bounds__(256) void k_gru_step(const float* __restrict__ h_prev,
                                                  int hp_stride,
                                                  const float* __restrict__ giV,
                                                  const int* __restrict__ trg,
                                                  const float* __restrict__ W_hh,
                                                  const float* __restrict__ b_hh,
                                                  float* __restrict__ h_all,
                                                  int t) {
    __shared__ float hs[8][520];
    int tid = threadIdx.x;
    int jc = blockIdx.x & 63, bc = blockIdx.x >> 6;
    int b0 = bc * 8;

#pragma unroll
    for (int i = 0; i < 4; ++i) {
        int fi = tid + i * 256;
        int bl2 = fi >> 7, k4 = fi & 127;
        float4 v = *(const float4*)(h_prev + (size_t)(b0 + bl2) * hp_stride + k4 * 4);
        *(float4*)&hs[bl2][k4 * 4] = v;
    }
    __syncthreads();

    int bl = tid & 7;
    int ks = (tid >> 3) & 3;
    int jl = tid >> 5;
    int j  = jc * 8 + jl;
    int k0 = ks * 128;

    const float4* w0 = (const float4*)(W_hh + (size_t)(j         ) * H_ + k0);
    const float4* w1 = (const float4*)(W_hh + (size_t)(j +   H_  ) * H_ + k0);
    const float4* w2 = (const float4*)(W_hh + (size_t)(j + 2 * H_) * H_ + k0);
    const float4* h4 = (const float4*)&hs[bl][k0];

    float sr = 0.f, sz = 0.f, sn = 0.f;
#pragma unroll 8
    for (int k = 0; k < 32; ++k) {
        float4 hv = h4[k];
        float4 a = w0[k], c = w1[k], d = w2[k];
        sr += hv.x * a.x + hv.y * a.y + hv.z * a.z + hv.w * a.w;
        sz += hv.x * c.x + hv.y * c.y + hv.z * c.z + hv.w * c.w;
        sn += hv.x * d.x + hv.y * d.y + hv.z * d.z + hv.w * d.w;
    }
    sr += __shfl_xor(sr, 8);  sr += __shfl_xor(sr, 16);
    sz += __shfl_xor(sz, 8);  sz += __shfl_xor(sz, 16);
    sn += __shfl_xor(sn, 8);  sn += __shfl_xor(sn, 16);

    if (ks == 0) {
        int b = b0 + bl;
        int tok = trg[(size_t)b * TT_ + t];
        const float* gv = giV + (size_t)tok * G3_;
        float gh_r = sr + b_hh[j];
        float gh_z = sz + b_hh[H_ + j];
        float gh_n = sn + b_hh[2 * H_ + j];
        float r = 1.f / (1.f + expf(-(gv[j] + gh_r)));
        float z = 1.f / (1.f + expf(-(gv[H_ + j] + gh_z)));
        float n = tanhf(gv[2 * H_ + j] + r * gh_n);
        float hp = hs[bl][j];
        h_all[(size_t)b * TT_ * H_ + (size_t)t * H_ + j] = (1.f - z) * n + z * hp;
    }
}

// FMA micro-kernel helper for the 4x4 register tiles
#define FMA16(a, bb)                                                     \
    acc[0][0] = fmaf(a.x, bb.x, acc[0][0]);                              \
    acc[0][1] = fmaf(a.x, bb.y, acc[0][1]);                              \
    acc[0][2] = fmaf(a.x, bb.z, acc[0][2]);                              \
    acc[0][3] = fmaf(a.x, bb.w, acc[0][3]);                              \
    acc[1][0] = fmaf(a.y, bb.x, acc[1][0]);                              \
    acc[1][1] = fmaf(a.y, bb.y, acc[1][1]);                              \
    acc[1][2] = fmaf(a.y, bb.z, acc[1][2]);                              \
    acc[1][3] = fmaf(a.y, bb.w, acc[1][3]);                              \
    acc[2][0] = fmaf(a.z, bb.x, acc[2][0]);                              \
    acc[2][1] = fmaf(a.z, bb.y, acc[2][1]);                              \
    acc[2][2] = fmaf(a.z, bb.z, acc[2][2]);                              \
    acc[2][3] = fmaf(a.z, bb.w, acc[2][3]);                              \
    acc[3][0] = fmaf(a.w, bb.x, acc[3][0]);                              \
    acc[3][1] = fmaf(a.w, bb.y, acc[3][1]);                              \
    acc[3][2] = fmaf(a.w, bb.z, acc[3][2]);                              \
    acc[3][3] = fmaf(a.w, bb.w, acc[3][3]);

// ---------------------------------------------------------------------------
// K2: scores[b, t, s] = sum_k h_all[b,t,k] * enc[b,s,k]   (NT GEMM per batch)
// ---------------------------------------------------------------------------
__global__ __launch_bounds__(256) void k_scores(const float* __restrict__ h_all,
                                                const float* __restrict__ enc,
                                                float* __restrict__ wgt) {
    __shared__ float As[16][68];
    __shared__ float Bs[16][68];
    int b  = blockIdx.z;
    int m0 = blockIdx.y * 64, n0 = blockIdx.x * 64;
    int tid = threadIdx.x;
    int tx = tid & 15, ty = tid >> 4;
    int lr = tid >> 2, lk = (tid & 3) * 4;

    const float* Abase = h_all + (size_t)b * TT_ * H_ + (size_t)(m0 + lr) * H_ + lk;
    const float* Bbase = enc   + (size_t)b * ST_ * H_ + (size_t)(n0 + lr) * H_ + lk;

    float acc[4][4] = {};
    for (int k0 = 0; k0 < H_; k0 += 16) {
        float4 av = *(const float4*)(Abase + k0);
        float4 bv = *(const float4*)(Bbase + k0);
        __syncthreads();
        As[lk + 0][lr] = av.x; As[lk + 1][lr] = av.y;
        As[lk + 2][lr] = av.z; As[lk + 3][lr] = av.w;
        Bs[lk + 0][lr] = bv.x; Bs[lk + 1][lr] = bv.y;
        Bs[lk + 2][lr] = bv.z; Bs[lk + 3][lr] = bv.w;
        __syncthreads();
#pragma unroll
        for (int kk = 0; kk < 16; ++kk) {
            float4 a  = *(const float4*)&As[kk][ty * 4];
            float4 bb = *(const float4*)&Bs[kk][tx * 4];
            FMA16(a, bb)
        }
    }
#pragma unroll
    for (int i = 0; i < 4; ++i)
#pragma unroll
        for (int jj = 0; jj < 4; ++jj)
            wgt[(size_t)b * TT_ * ST_ + (size_t)(m0 + ty * 4 + i) * ST_ + (n0 + tx * 4 + jj)] = acc[i][jj];
}

// ---------------------------------------------------------------------------
// K3: masked softmax over s (row length 1024). One block per (b, t) row.
// ---------------------------------------------------------------------------
__global__ __launch_bounds__(256) void k_softmax(float* __restrict__ wgt,
                                                 const int* __restrict__ source_len) {
    __shared__ float red[8];
    int row = blockIdx.x;            // b*TT + t
    int b = row >> 8;
    int slen = source_len[b];
    float* W = wgt + (size_t)row * ST_;
    int tid = threadIdx.x;

    float v[4];
    float mx = -3.0e38f;
#pragma unroll
    for (int i = 0; i < 4; ++i) {
        int s = tid + i * 256;
        v[i] = (s < slen) ? W[s] : -1e9f;
        mx = fmaxf(mx, v[i]);
    }
#pragma unroll
    for (int off = 32; off; off >>= 1) mx = fmaxf(mx, __shfl_xor(mx, off));
    int wv = tid >> 6;
    if ((tid & 63) == 0) red[wv] = mx;
    __syncthreads();
    mx = fmaxf(fmaxf(red[0], red[1]), fmaxf(red[2], red[3]));

    float sm = 0.f;
#pragma unroll
    for (int i = 0; i < 4; ++i) {
        v[i] = expf(v[i] - mx);
        sm += v[i];
    }
#pragma unroll
    for (int off = 32; off; off >>= 1) sm += __shfl_xor(sm, off);
    if ((tid & 63) == 0) red[4 + wv] = sm;
    __syncthreads();
    sm = red[4] + red[5] + red[6] + red[7];
    float inv = 1.f / sm;
#pragma unroll
    for (int i = 0; i < 4; ++i)
        W[tid + i * 256] = v[i] * inv;
}

// ---------------------------------------------------------------------------
// K4: ctx[b, t, n] = sum_s wgt[b,t,s] * enc[b,s,n]   (NN GEMM per batch)
// ---------------------------------------------------------------------------
__global__ __launch_bounds__(256) void k_ctx(const float* __restrict__ wgt,
                                             const float* __restrict__ enc,
                                             float* __restrict__ ctx) {
    __shared__ float As[16][68];
    __shared__ float Bs[16][68];
    int b  = blockIdx.z;
    int m0 = blockIdx.y * 64, n0 = blockIdx.x * 64;
    int tid = threadIdx.x;
    int tx = tid & 15, ty = tid >> 4;
    int lr = tid >> 2, lk = (tid & 3) * 4;     // A-tile load mapping
    int bk = tid >> 4, bn = (tid & 15) * 4;    // B-tile load mapping

    const float* Abase = wgt + (size_t)b * TT_ * ST_ + (size_t)(m0 + lr) * ST_ + lk;
    const float* Bbase = enc + (size_t)b * ST_ * H_ + n0 + bn;

    float acc[4][4] = {};
    for (int k0 = 0; k0 < ST_; k0 += 16) {
        float4 av = *(const float4*)(Abase + k0);
        float4 bv = *(const float4*)(Bbase + (size_t)(k0 + bk) * H_);
        __syncthreads();
        As[lk + 0][lr] = av.x; As[lk + 1][lr] = av.y;
        As[lk + 2][lr] = av.z; As[lk + 3][lr] = av.w;
        *(float4*)&Bs[bk][bn] = bv;
        __syncthreads();
#pragma unroll
        for (int kk = 0; kk < 16; ++kk) {
            float4 a  = *(const float4*)&As[kk][ty * 4];
            float4 bb = *(const float4*)&Bs[kk][tx * 4];
            FMA16(a, bb)
        }
    }
#pragma unroll
    for (int i = 0; i < 4; ++i)
#pragma unroll
        for (int jj = 0; jj < 4; ++jj)
            ctx[(size_t)b * TT_ * H_ + (size_t)(m0 + ty * 4 + i) * H_ + (n0 + tx * 4 + jj)] = acc[i][jj];
}

// ---------------------------------------------------------------------------
// K5: out[b,t,o] = (t < trg_len[b]) ? [h|ctx] . fc_W[o] + fc_b[o] : 0
// ---------------------------------------------------------------------------
__global__ __launch_bounds__(256) void k_out(const float* __restrict__ h_all,
                                             const float* __restrict__ ctx,
                                             const float* __restrict__ fc_Wt,
                                             const float* __restrict__ fc_b,
                                             const int* __restrict__ trg_len,
                                             float* __restrict__ out) {
    int tid = threadIdx.x;
    int o = tid & 31;
    int m = blockIdx.x * 8 + (tid >> 5);     // b*TT + t
    int b = m >> 8, t = m & 255;
    const float* xh = h_all + (size_t)m * H_;
    const float* xc = ctx + (size_t)m * H_;
    float acc = (o < O_) ? fc_b[o] : 0.f;
#pragma unroll 4
    for (int k = 0; k < H_; ++k) acc = fmaf(xh[k], fc_Wt[k * 32 + o], acc);
#pragma unroll 4
    for (int k = 0; k < H_; ++k) acc = fmaf(xc[k], fc_Wt[(H_ + k) * 32 + o], acc);
    if (o < O_) {
        float val = (t < trg_len[b]) ? acc : 0.0f;
        out[(size_t)m * O_ + o] = val;
    }
}

// ---------------------------------------------------------------------------
extern "C" void kernel_launch(void* const* d_in, const int* in_sizes, int n_in,
                              void* d_out, int out_size, void* d_ws, size_t ws_size,
                              hipStream_t stream) {
    const int*   trg      = (const int*)d_in[0];
    const int*   trg_len  = (const int*)d_in[1];
    const int*   src_len  = (const int*)d_in[2];
    const float* enc      = (const float*)d_in[3];
    const float* enc_last = (const float*)d_in[4];
    const float* embed    = (const float*)d_in[5];
    const float* W_ih     = (const float*)d_in[6];
    const float* W_hh     = (const float*)d_in[7];
    const float* b_ih     = (const float*)d_in[8];
    const float* b_hh     = (const float*)d_in[9];
    const float* fc_W     = (const float*)d_in[10];
    const float* fc_b     = (const float*)d_in[11];
    float* out = (float*)d_out;

    char* ws = (char*)d_ws;
    float* giV   = (float*)ws;  ws += (size_t)V_ * G3_ * 4;            // 192 KB
    float* fc_Wt = (float*)ws;  ws += (size_t)1024 * 32 * 4;           // 128 KB
    float* h_all = (float*)ws;  ws += (size_t)B_ * TT_ * H_ * 4;       // 32 MB
    float* wgt   = (float*)ws;  ws += (size_t)B_ * TT_ * ST_ * 4;      // 64 MB
    float* ctx   = (float*)ws;  ws += (size_t)B_ * TT_ * H_ * 4;       // 32 MB
    unsigned* flags = (unsigned*)ws;
    ws += (size_t)TT_ * NGRP_ * NJC_ * 4;                              // 256 KB

    k_giv<<<192, 256, 0, stream>>>(embed, W_ih, b_ih, giV);
    k_fcw_t<<<128, 256, 0, stream>>>(fc_W, fc_Wt, flags);

    // ---- persistent GRU (co-residency via cooperative launch; flag sync) ----
    void* kargs[7];
    kargs[0] = (void*)&enc_last;
    kargs[1] = (void*)&giV;
    kargs[2] = (void*)&trg;
    kargs[3] = (void*)&W_hh;
    kargs[4] = (void*)&b_hh;
    kargs[5] = (void*)&h_all;
    kargs[6] = (void*)&flags;
    hipError_t ce = hipLaunchCooperativeKernel((const void*)k_gru_persist,
                                               dim3(256), dim3(512),
                                               kargs, 0, stream);
    if (ce != hipSuccess) {
        (void)hipGetLastError();   // clear error; fall back to per-step loop
        for (int t = 0; t < TT_; ++t) {
            const float* hp = t ? (h_all + (size_t)(t - 1) * H_) : enc_last;
            int stride = t ? TT_ * H_ : H_;
            k_gru_step<<<512, 256, 0, stream>>>(hp, stride, giV, trg, W_hh, b_hh, h_all, t);
        }
    }

    k_scores<<<dim3(ST_ / 64, TT_ / 64, B_), 256, 0, stream>>>(h_all, enc, wgt);
    k_softmax<<<B_ * TT_, 256, 0, stream>>>(wgt, src_len);
    k_ctx<<<dim3(H_ / 64, TT_ / 64, B_), 256, 0, stream>>>(wgt, enc, ctx);
    k_out<<<B_ * TT_ / 8, 256, 0, stream>>>(h_all, ctx, fc_Wt, fc_b, trg_len, out);
}